// Round 2
// baseline (189.090 us; speedup 1.0000x reference)
//
#include <hip/hip_runtime.h>

#define Tt 2048
#define Cc 512
#define Bb 4
#define BC (Bb * Cc)

typedef __attribute__((ext_vector_type(4))) float f32x4;
typedef __attribute__((ext_vector_type(8))) _Float16 f16x8;
typedef __attribute__((ext_vector_type(4))) _Float16 f16x4;
typedef __attribute__((ext_vector_type(2))) _Float16 f16x2;

// ---------------------------------------------------------------------------
// Kernel 0: W[k][n] (x4) -> Wt[z][n][k] fp16 (single plane).
// ---------------------------------------------------------------------------
__global__ __launch_bounds__(256) void wsetup(
    const float* __restrict__ Wq, const float* __restrict__ Wk,
    const float* __restrict__ Wv, const float* __restrict__ Wo,
    _Float16* __restrict__ Wt)
{
    const int z = blockIdx.y;
    const float* W = (z == 0) ? Wq : (z == 1) ? Wk : (z == 2) ? Wv : Wo;
    const int k0 = (blockIdx.x >> 3) * 64, n0 = (blockIdx.x & 7) * 64;
    const int tid = threadIdx.x;
    __shared__ float tile[64][65];

#pragma unroll
    for (int i = 0; i < 4; ++i) {
        const int idx = i * 256 + tid;
        const int kr = idx >> 4, c4 = idx & 15;
        float4 v = *(const float4*)&W[(size_t)(k0 + kr) * Cc + n0 + c4 * 4];
        tile[kr][c4 * 4 + 0] = v.x; tile[kr][c4 * 4 + 1] = v.y;
        tile[kr][c4 * 4 + 2] = v.z; tile[kr][c4 * 4 + 3] = v.w;
    }
    __syncthreads();
#pragma unroll
    for (int i = 0; i < 4; ++i) {
        const int idx = i * 256 + tid;
        const int nr = idx >> 4, k4 = idx & 15;
        f16x4 o;
        o[0] = (_Float16)tile[k4 * 4 + 0][nr];
        o[1] = (_Float16)tile[k4 * 4 + 1][nr];
        o[2] = (_Float16)tile[k4 * 4 + 2][nr];
        o[3] = (_Float16)tile[k4 * 4 + 3][nr];
        *(f16x4*)&Wt[((size_t)(z * 512 + n0 + nr)) * Cc + k0 + k4 * 4] = o;
    }
}

// ---------------------------------------------------------------------------
// Kernel 1: QKV GEMM, single-term fp16 MFMA. 128x128 tile, 4 waves, BK=32.
// Epilogue: fp16 store + per-(b,channel) column sum-of-squares (fp32 acc).
// ---------------------------------------------------------------------------
__global__ __launch_bounds__(256, 3) void qkv_mfma(
    const float* __restrict__ HS, const _Float16* __restrict__ Wt,
    _Float16* __restrict__ Qf, _Float16* __restrict__ Kf,
    _Float16* __restrict__ Vf, float* __restrict__ colsum)
{
    const int mt = blockIdx.x;              // 64
    const int nt = blockIdx.y;              // 4
    const int z  = blockIdx.z;              // 3
    _Float16* Out = (z == 0) ? Qf : (z == 1) ? Kf : Vf;

    const int tid = threadIdx.x;
    const int wave = tid >> 6, lane = tid & 63;
    const int quad = lane >> 4, lm = lane & 15;
    const int wm = (wave & 1) * 64, wn = (wave >> 1) * 64;

    __shared__ _Float16 sA[128 * 40];
    __shared__ _Float16 sB[128 * 40];

    f32x4 acc[4][4];
#pragma unroll
    for (int mf = 0; mf < 4; ++mf)
#pragma unroll
        for (int nf = 0; nf < 4; ++nf) acc[mf][nf] = (f32x4){0.f, 0.f, 0.f, 0.f};

    const int r2 = tid >> 1, kc = (tid & 1) * 16;
    const float* ga = HS + (size_t)(mt * 128 + r2) * Cc + kc;
    const _Float16* gb = Wt + ((size_t)(z * 512 + nt * 128 + r2)) * Cc + kc;

    for (int k0 = 0; k0 < Cc; k0 += 32) {
        __syncthreads();
        {
            float4 a0 = *(const float4*)&ga[k0];
            float4 a1 = *(const float4*)&ga[k0 + 4];
            float4 a2 = *(const float4*)&ga[k0 + 8];
            float4 a3 = *(const float4*)&ga[k0 + 12];
            f16x8 h0, h1;
            h0[0] = (_Float16)a0.x; h0[1] = (_Float16)a0.y;
            h0[2] = (_Float16)a0.z; h0[3] = (_Float16)a0.w;
            h0[4] = (_Float16)a1.x; h0[5] = (_Float16)a1.y;
            h0[6] = (_Float16)a1.z; h0[7] = (_Float16)a1.w;
            h1[0] = (_Float16)a2.x; h1[1] = (_Float16)a2.y;
            h1[2] = (_Float16)a2.z; h1[3] = (_Float16)a2.w;
            h1[4] = (_Float16)a3.x; h1[5] = (_Float16)a3.y;
            h1[6] = (_Float16)a3.z; h1[7] = (_Float16)a3.w;
            *(f16x8*)&sA[r2 * 40 + kc]     = h0;
            *(f16x8*)&sA[r2 * 40 + kc + 8] = h1;
            *(f16x8*)&sB[r2 * 40 + kc]     = *(const f16x8*)&gb[k0];
            *(f16x8*)&sB[r2 * 40 + kc + 8] = *(const f16x8*)&gb[k0 + 8];
        }
        __syncthreads();

        f16x8 ah[4], bh[4];
#pragma unroll
        for (int mf = 0; mf < 4; ++mf)
            ah[mf] = *(const f16x8*)&sA[(wm + mf * 16 + lm) * 40 + quad * 8];
#pragma unroll
        for (int nf = 0; nf < 4; ++nf)
            bh[nf] = *(const f16x8*)&sB[(wn + nf * 16 + lm) * 40 + quad * 8];
#pragma unroll
        for (int mf = 0; mf < 4; ++mf)
#pragma unroll
            for (int nf = 0; nf < 4; ++nf)
                acc[mf][nf] = __builtin_amdgcn_mfma_f32_16x16x32_f16(ah[mf], bh[nf], acc[mf][nf], 0, 0, 0);
    }

    const int bidx = mt >> 4;
#pragma unroll
    for (int nf = 0; nf < 4; ++nf) {
        float cs = 0.f;
#pragma unroll
        for (int mf = 0; mf < 4; ++mf)
#pragma unroll
            for (int r = 0; r < 4; ++r) {
                const float v = acc[mf][nf][r];
                const size_t idx =
                    (size_t)(mt * 128 + wm + mf * 16 + quad * 4 + r) * Cc +
                    nt * 128 + wn + nf * 16 + lm;
                Out[idx] = (_Float16)v;
                cs += v * v;
            }
        cs += __shfl_xor(cs, 16, 64);
        cs += __shfl_xor(cs, 32, 64);
        if (lane < 16)
            atomicAdd(&colsum[(size_t)z * BC + bidx * Cc + nt * 128 + wn + nf * 16 + lane], cs);
    }
}

// ---------------------------------------------------------------------------
// Kernel 2: colsum -> 1/sqrt(mean + eps)
// ---------------------------------------------------------------------------
__global__ void inv_norm_kernel(const float* __restrict__ colsum,
                                float* __restrict__ inv)
{
    const int i = blockIdx.x * blockDim.x + threadIdx.x;
    if (i < 3 * BC) inv[i] = rsqrtf(colsum[i] * (1.0f / Tt) + 1e-4f);
}

// ---------------------------------------------------------------------------
// Kernel 3: V[b][t][c] fp16 -> VT[b][c][t] fp16 (pure transpose; iv folded
// into attn epilogue).
// ---------------------------------------------------------------------------
__global__ __launch_bounds__(256) void norm_vt(
    const _Float16* __restrict__ V, _Float16* __restrict__ VT)
{
    const int blk = blockIdx.x;          // 4 * 8 * 32 = 1024
    const int b = blk >> 8, ct = (blk >> 5) & 7, tt = blk & 31;
    const int t0 = tt * 64, c0 = ct * 64;
    const int tid = threadIdx.x;

    __shared__ _Float16 tile[64 * 72];

#pragma unroll
    for (int i = 0; i < 2; ++i) {
        const int idx = i * 256 + tid;
        const int tr = idx >> 3, c8 = (idx & 7) * 8;
        *(f16x8*)&tile[tr * 72 + c8] =
            *(const f16x8*)&V[(size_t)(b * Tt + t0 + tr) * Cc + c0 + c8];
    }
    __syncthreads();
#pragma unroll
    for (int i = 0; i < 2; ++i) {
        const int idx = i * 256 + tid;
        const int cr = idx >> 3, t8 = (idx & 7) * 8;
        f16x8 o;
#pragma unroll
        for (int j = 0; j < 8; ++j) o[j] = tile[(t8 + j) * 72 + cr];
        *(f16x8*)&VT[(size_t)(b * Cc + c0 + cr) * Tt + t0 + t8] = o;
    }
}

// ---------------------------------------------------------------------------
// Kernel 4: fp16 MFMA flash attention, transposed (S^T / O^T) form.
// 512 threads / 8 waves, 16 queries per wave (occupancy: 2 blk/CU x 8 waves
// = 16 waves/CU vs 8 before). iq*ik*scale*log2(e) folded into Q frags ->
// p = exp2(s) via v_exp_f32 directly; cvt_pkrtz packs P. iv folded into
// epilogue.
// ---------------------------------------------------------------------------
#define LSTR 72

__global__ __launch_bounds__(512, 4) void attn_mfma(
    const _Float16* __restrict__ Qf, const _Float16* __restrict__ Kf,
    const _Float16* __restrict__ VT, const float* __restrict__ inv,
    _Float16* __restrict__ AO)
{
    const int qt = blockIdx.x;            // 16
    const int bh = blockIdx.y;            // 32
    const int b = bh >> 3, h = bh & 7;
    const int tid = threadIdx.x;
    const int wave = tid >> 6, lane = tid & 63;
    const int quad = lane >> 4, lm = lane & 15;

    __shared__ _Float16 sK[64 * LSTR];
    __shared__ _Float16 sVT[64 * LSTR];
    __shared__ _Float16 sP[8 * 16 * LSTR];
    _Float16* myP = sP + wave * 16 * LSTR;

    // ---- Q fragments (B-operand: n=lm=query, k=quad*8+j)
    // iq*ik*0.125*log2(e) folded -> exp2 downstream.
    f16x8 qb[2];
    {
        const float* iqp = inv + b * Cc + h * 64;
        const float* ikp = inv + BC + b * Cc + h * 64;
        const int row = qt * 128 + wave * 16 + lm;
#pragma unroll
        for (int ks = 0; ks < 2; ++ks) {
            const int d0 = ks * 32 + quad * 8;
            f16x8 qv = *(const f16x8*)&Qf[(size_t)(b * Tt + row) * Cc + h * 64 + d0];
#pragma unroll
            for (int j = 0; j < 8; ++j) {
                const float f = (float)qv[j] * iqp[d0 + j] * ikp[d0 + j] * 0.18033688011f;
                qb[ks][j] = (_Float16)f;
            }
        }
    }

    f32x4 o[4];          // [cf]: O^T frags, m=channel, n=query
#pragma unroll
    for (int cf = 0; cf < 4; ++cf) o[cf] = (f32x4){0.f, 0.f, 0.f, 0.f};
    float ls = 0.f;

    const int sr = tid >> 3, sc = (tid & 7) * 8;
    const _Float16* gK = Kf + (size_t)b * Tt * Cc + h * 64;
    const _Float16* gV = VT + ((size_t)b * Cc + h * 64) * Tt;

    f16x8 rk, rv;
    {
        rk = *(const f16x8*)&gK[(size_t)sr * Cc + sc];
        rv = *(const f16x8*)&gV[(size_t)sr * Tt + sc];
    }

    for (int kt = 0; kt < 32; ++kt) {
        __syncthreads();
        *(f16x8*)&sK[sr * LSTR + sc] = rk;
        *(f16x8*)&sVT[sr * LSTR + sc] = rv;
        __syncthreads();

        if (kt < 31) {
            const int t0 = (kt + 1) * 64;
            rk = *(const f16x8*)&gK[(size_t)(t0 + sr) * Cc + sc];
            rv = *(const f16x8*)&gV[(size_t)sr * Tt + t0 + sc];
        }

        // ---- S^T = K Q^T  (m=key, n=query)
        f32x4 st[4];
#pragma unroll
        for (int kf = 0; kf < 4; ++kf) st[kf] = (f32x4){0.f, 0.f, 0.f, 0.f};
#pragma unroll
        for (int ks = 0; ks < 2; ++ks) {
            f16x8 ka[4];
#pragma unroll
            for (int kf = 0; kf < 4; ++kf)
                ka[kf] = *(const f16x8*)&sK[(kf * 16 + lm) * LSTR + ks * 32 + quad * 8];
#pragma unroll
            for (int kf = 0; kf < 4; ++kf)
                st[kf] = __builtin_amdgcn_mfma_f32_16x16x32_f16(ka[kf], qb[ks], st[kf], 0, 0, 0);
        }

        // ---- p = exp2(s); P rows packed b64; l partials
#pragma unroll
        for (int kf = 0; kf < 4; ++kf) {
            const float p0 = __builtin_amdgcn_exp2f(st[kf][0]);
            const float p1 = __builtin_amdgcn_exp2f(st[kf][1]);
            const float p2 = __builtin_amdgcn_exp2f(st[kf][2]);
            const float p3 = __builtin_amdgcn_exp2f(st[kf][3]);
            ls += (p0 + p1) + (p2 + p3);
            const f16x2 lo = __builtin_bit_cast(f16x2, __builtin_amdgcn_cvt_pkrtz(p0, p1));
            const f16x2 hi = __builtin_bit_cast(f16x2, __builtin_amdgcn_cvt_pkrtz(p2, p3));
            f16x4 pk;
            pk[0] = lo[0]; pk[1] = lo[1]; pk[2] = hi[0]; pk[3] = hi[1];
            *(f16x4*)&myP[lm * LSTR + kf * 16 + quad * 4] = pk;
        }

        // ---- O^T += VT P^T
#pragma unroll
        for (int ks = 0; ks < 2; ++ks) {
            f16x8 pb = *(const f16x8*)&myP[lm * LSTR + ks * 32 + quad * 8];
            f16x8 va[4];
#pragma unroll
            for (int cf = 0; cf < 4; ++cf)
                va[cf] = *(const f16x8*)&sVT[(cf * 16 + lm) * LSTR + ks * 32 + quad * 8];
#pragma unroll
            for (int cf = 0; cf < 4; ++cf)
                o[cf] = __builtin_amdgcn_mfma_f32_16x16x32_f16(va[cf], pb, o[cf], 0, 0, 0);
        }
    }

    // ---- epilogue: l reduce over quads, O /= l, * iv (per-channel), fp16 out
    float il;
    {
        float s = ls;
        s += __shfl_xor(s, 16, 64);
        s += __shfl_xor(s, 32, 64);
        il = 1.0f / s;
    }
    const float* ivp = inv + 2 * BC + b * Cc + h * 64;
    float iv[4][4];
#pragma unroll
    for (int cf = 0; cf < 4; ++cf) {
        float4 t = *(const float4*)&ivp[cf * 16 + quad * 4];
        iv[cf][0] = t.x; iv[cf][1] = t.y; iv[cf][2] = t.z; iv[cf][3] = t.w;
    }
    {
        const size_t row = (size_t)(b * Tt + qt * 128 + wave * 16 + lm);
#pragma unroll
        for (int cf = 0; cf < 4; ++cf) {
            f16x4 pk;
#pragma unroll
            for (int r = 0; r < 4; ++r)
                pk[r] = (_Float16)(o[cf][r] * il * iv[cf][r]);
            *(f16x4*)&AO[row * Cc + h * 64 + cf * 16 + quad * 4] = pk;
        }
    }
}

// ---------------------------------------------------------------------------
// Kernel 5: out = AO @ Wo + bo + residual, single-term fp16 MFMA.
// 64x128 tile, 4 waves (each 32x64).
// ---------------------------------------------------------------------------
__global__ __launch_bounds__(256, 2) void out_mfma(
    const _Float16* __restrict__ AO, const _Float16* __restrict__ Wt,
    const float* __restrict__ bo, const float* __restrict__ HS,
    float* __restrict__ Outp)
{
    const int mt = blockIdx.x;              // 128
    const int nt = blockIdx.y;              // 4
    const int tid = threadIdx.x;
    const int wave = tid >> 6, lane = tid & 63;
    const int quad = lane >> 4, lm = lane & 15;
    const int wm = (wave & 1) * 32, wn = (wave >> 1) * 64;

    __shared__ _Float16 sA[64 * 40];
    __shared__ _Float16 sB[128 * 40];

    f32x4 acc[2][4];
#pragma unroll
    for (int mf = 0; mf < 2; ++mf)
#pragma unroll
        for (int nf = 0; nf < 4; ++nf) acc[mf][nf] = (f32x4){0.f, 0.f, 0.f, 0.f};

    const int ra = tid >> 2, ka = (tid & 3) * 8;
    const int rb = tid >> 1, kb = (tid & 1) * 16;
    const _Float16* gah = AO + (size_t)(mt * 64 + ra) * Cc + ka;
    const _Float16* gbh = Wt + ((size_t)(3 * 512 + nt * 128 + rb)) * Cc + kb;

    for (int k0 = 0; k0 < Cc; k0 += 32) {
        __syncthreads();
        {
            *(f16x8*)&sA[ra * 40 + ka] = *(const f16x8*)&gah[k0];
            *(f16x8*)&sB[rb * 40 + kb]     = *(const f16x8*)&gbh[k0];
            *(f16x8*)&sB[rb * 40 + kb + 8] = *(const f16x8*)&gbh[k0 + 8];
        }
        __syncthreads();

        f16x8 ah[2], bh[4];
#pragma unroll
        for (int mf = 0; mf < 2; ++mf)
            ah[mf] = *(const f16x8*)&sA[(wm + mf * 16 + lm) * 40 + quad * 8];
#pragma unroll
        for (int nf = 0; nf < 4; ++nf)
            bh[nf] = *(const f16x8*)&sB[(wn + nf * 16 + lm) * 40 + quad * 8];
#pragma unroll
        for (int mf = 0; mf < 2; ++mf)
#pragma unroll
            for (int nf = 0; nf < 4; ++nf)
                acc[mf][nf] = __builtin_amdgcn_mfma_f32_16x16x32_f16(ah[mf], bh[nf], acc[mf][nf], 0, 0, 0);
    }

#pragma unroll
    for (int mf = 0; mf < 2; ++mf)
#pragma unroll
        for (int r = 0; r < 4; ++r) {
            const size_t m = (size_t)(mt * 64 + wm + mf * 16 + quad * 4 + r);
#pragma unroll
            for (int nf = 0; nf < 4; ++nf) {
                const int col = nt * 128 + wn + nf * 16 + lm;
                Outp[m * Cc + col] = acc[mf][nf][r] + bo[col] + HS[m * Cc + col];
            }
        }
}

// ---------------------------------------------------------------------------
extern "C" void kernel_launch(void* const* d_in, const int* in_sizes, int n_in,
                              void* d_out, int out_size, void* d_ws,
                              size_t ws_size, hipStream_t stream)
{
    const float* HS = (const float*)d_in[0];
    const float* Wq = (const float*)d_in[1];
    const float* Wk = (const float*)d_in[2];
    const float* Wv = (const float*)d_in[3];
    const float* Wo = (const float*)d_in[4];
    const float* bo = (const float*)d_in[5];
    float* out = (float*)d_out;

    const size_t SZ = (size_t)Bb * Tt * Cc;        // 4,194,304 elements
    _Float16* Qf  = (_Float16*)d_ws;
    _Float16* Kf  = Qf + SZ;
    _Float16* Vf  = Kf + SZ;
    _Float16* VTh = Vf + SZ;
    _Float16* AO  = VTh + SZ;
    _Float16* Wt  = AO + SZ;                        // 4*Cc*Cc halves
    float* colsum = (float*)(Wt + 4 * Cc * Cc);
    float* inv    = colsum + 3 * BC;

    (void)hipMemsetAsync(colsum, 0, 3 * BC * sizeof(float), stream);

    wsetup<<<dim3(64, 4), 256, 0, stream>>>(Wq, Wk, Wv, Wo, Wt);

    qkv_mfma<<<dim3(64, 4, 3), 256, 0, stream>>>(HS, Wt, Qf, Kf, Vf, colsum);

    inv_norm_kernel<<<(3 * BC + 255) / 256, 256, 0, stream>>>(colsum, inv);

    norm_vt<<<1024, 256, 0, stream>>>(Vf, VTh);

    attn_mfma<<<dim3(16, 32), 512, 0, stream>>>(Qf, Kf, VTh, inv, AO);

    out_mfma<<<dim3(128, 4), 256, 0, stream>>>(AO, Wt, bo, HS, out);
}